// Round 1
// baseline (939.158 us; speedup 1.0000x reference)
//
#include <hip/hip_runtime.h>
#include <hip/hip_bf16.h>
#include <math.h>

typedef unsigned short u16;
typedef __bf16 bf16x8 __attribute__((ext_vector_type(8)));
typedef float f32x4 __attribute__((ext_vector_type(4)));

#define B_   8
#define NQ   1024
#define NC   2048
#define IND  768
#define DIM  384
#define NH   6
#define HD   64
#define HID  3072

__device__ __forceinline__ u16 f2b(float f){
  unsigned int x = __float_as_uint(f);
  return (u16)((x + 0x7fffu + ((x >> 16) & 1u)) >> 16);
}

// ---- weight convert+transpose: W (K x N) fp32 -> Wt (N x K) bf16 ----
__global__ void wtrans_kernel(const float* __restrict__ W, u16* __restrict__ Wt,
                              int K, int N){
  __shared__ float tile[32][33];
  int n0 = blockIdx.x * 32, k0 = blockIdx.y * 32;
  int tx = threadIdx.x, ty = threadIdx.y;   // 32 x 8
  #pragma unroll
  for(int i=0;i<4;i++) tile[ty*4+i][tx] = W[(size_t)(k0+ty*4+i)*N + n0 + tx];
  __syncthreads();
  #pragma unroll
  for(int i=0;i<4;i++) Wt[(size_t)(n0+ty*4+i)*K + k0 + tx] = f2b(tile[tx][ty*4+i]);
}

// ---- layernorm over rows of 768: fp32 in -> bf16 out (+optional fp32 out) ----
template<bool ALSO_F32>
__global__ void ln_kernel(const float* __restrict__ x, const float* __restrict__ w,
                          const float* __restrict__ bia, u16* __restrict__ yb,
                          float* __restrict__ yf){
  int row = blockIdx.x;
  const float* xr = x + (size_t)row * IND;
  int t = threadIdx.x;
  float v[3];
  v[0] = xr[t]; v[1] = xr[t+256]; v[2] = xr[t+512];
  float s  = v[0]+v[1]+v[2];
  float sq = v[0]*v[0]+v[1]*v[1]+v[2]*v[2];
  #pragma unroll
  for(int o=1;o<64;o<<=1){ s += __shfl_xor(s, o, 64); sq += __shfl_xor(sq, o, 64); }
  __shared__ float ss[4], ssq[4];
  int wid = t >> 6;
  if((t&63)==0){ ss[wid]=s; ssq[wid]=sq; }
  __syncthreads();
  s  = ss[0]+ss[1]+ss[2]+ss[3];
  sq = ssq[0]+ssq[1]+ssq[2]+ssq[3];
  float mean = s * (1.0f/IND);
  float var  = sq * (1.0f/IND) - mean*mean;
  float rs   = rsqrtf(var + 1e-5f);
  #pragma unroll
  for(int i=0;i<3;i++){
    int idx = t + i*256;
    float y = (v[i]-mean)*rs*w[idx] + bia[idx];
    yb[(size_t)row*IND + idx] = f2b(y);
    if(ALSO_F32) yf[(size_t)row*IND + idx] = y;
  }
}

// ---- NT GEMM: C(rows x N) = A(rows x K) @ Wt(N x K)^T, bf16 MFMA 16x16x32 ----
// OUTM: 0 = bf16 out, 1 = fp32 out, 2 = fp32 residual accumulate (C += ...)
template<int OUTM, bool BIAS, bool GELU_>
__global__ __launch_bounds__(256) void gemm_bt(const u16* __restrict__ A,
    const u16* __restrict__ Wt, const float* __restrict__ bias,
    void* __restrict__ C, int K, int N){
  __shared__ __align__(16) u16 As[128][40];   // +8 pad: 2-way bank alias (free)
  __shared__ __align__(16) u16 Bs[128][40];
  int rowblk = blockIdx.x * 128, colblk = blockIdx.y * 128;
  int tid = threadIdx.x;
  int lane = tid & 63, wv = tid >> 6;
  int wm = (wv >> 1) * 64, wn = (wv & 1) * 64;
  int l16 = lane & 15, quad = lane >> 4;
  f32x4 acc[4][4] = {};
  int r = tid >> 2, c8 = (tid & 3) * 8;
  const u16* Ap = A  + (size_t)(rowblk + r) * K + c8;
  const u16* Bp = Wt + (size_t)(colblk + r) * K + c8;
  for(int kt = 0; kt < K; kt += 32){
    int4 a0 = *(const int4*)(Ap + kt);
    int4 a1 = *(const int4*)(Ap + (size_t)64 * K + kt);
    int4 b0 = *(const int4*)(Bp + kt);
    int4 b1 = *(const int4*)(Bp + (size_t)64 * K + kt);
    *(int4*)&As[r][c8]    = a0;
    *(int4*)&As[r+64][c8] = a1;
    *(int4*)&Bs[r][c8]    = b0;
    *(int4*)&Bs[r+64][c8] = b1;
    __syncthreads();
    bf16x8 af[4], bfr[4];
    #pragma unroll
    for(int i=0;i<4;i++) af[i]  = *(const bf16x8*)&As[wm + i*16 + l16][quad*8];
    #pragma unroll
    for(int j=0;j<4;j++) bfr[j] = *(const bf16x8*)&Bs[wn + j*16 + l16][quad*8];
    #pragma unroll
    for(int i=0;i<4;i++)
      #pragma unroll
      for(int j=0;j<4;j++)
        acc[i][j] = __builtin_amdgcn_mfma_f32_16x16x32_bf16(af[i], bfr[j], acc[i][j], 0, 0, 0);
    __syncthreads();
  }
  #pragma unroll
  for(int i=0;i<4;i++){
    #pragma unroll
    for(int j=0;j<4;j++){
      int grow = rowblk + wm + i*16 + quad*4;
      int gcol = colblk + wn + j*16 + l16;
      float bv = BIAS ? bias[gcol] : 0.0f;
      #pragma unroll
      for(int rg=0; rg<4; rg++){
        float vval = acc[i][j][rg] + bv;
        if(GELU_) vval = 0.5f * vval * (1.0f + erff(vval * 0.70710678118f));
        size_t idx = (size_t)(grow + rg) * N + gcol;
        if(OUTM == 0)      ((u16*)C)[idx]   = f2b(vval);
        else if(OUTM == 1) ((float*)C)[idx] = vval;
        else               ((float*)C)[idx] += vval;
      }
    }
  }
}

// ---- flash attention: per (b, h, 64-row q-tile); each wave owns 16 q rows ----
__global__ __launch_bounds__(256) void attn_kernel(const u16* __restrict__ Q,
    const u16* __restrict__ KV, u16* __restrict__ AO, int M){
  __shared__ __align__(16) u16 Ks[64][72];       // K chunk [ctx][d]
  __shared__ __align__(16) u16 Vt[64][72];       // V chunk transposed [d][ctx]
  __shared__ __align__(16) u16 Ps[4][16][72];    // per-wave P round-trip
  int blk = blockIdx.x;
  int qt = blk & 15; int bh = blk >> 4; int h = bh % NH; int b = bh / NH;
  int tid = threadIdx.x, lane = tid & 63, wv = tid >> 6;
  int l16 = lane & 15, quad = lane >> 4;
  const u16* qptr = Q + (size_t)(b*NQ + qt*64 + wv*16 + l16) * DIM + h*HD;
  bf16x8 aq0 = *(const bf16x8*)(qptr + quad*8);
  bf16x8 aq1 = *(const bf16x8*)(qptr + 32 + quad*8);
  f32x4 o[4] = {};
  float mrow[4] = {-3e38f,-3e38f,-3e38f,-3e38f};
  float lrow[4] = {0.f,0.f,0.f,0.f};
  const float scale = 0.125f;   // 64^-0.5
  for(int cb = 0; cb < M; cb += 64){
    __syncthreads();   // previous chunk's PV reads done
    #pragma unroll
    for(int it=0; it<2; it++){
      int idx = tid + it*256;
      int rr = idx >> 3, cc8 = (idx & 7) * 8;
      const u16* kvp = KV + (size_t)(b*M + cb + rr) * (2*DIM) + h*HD;
      *(int4*)&Ks[rr][cc8] = *(const int4*)(kvp + cc8);
      int4 vvv = *(const int4*)(kvp + DIM + cc8);
      u16 vs[8]; *(int4*)vs = vvv;
      #pragma unroll
      for(int j=0;j<8;j++) Vt[cc8+j][rr] = vs[j];
    }
    __syncthreads();
    // S = Q K^T over d=64 (two k=32 MFMAs), 4 ctx-subtiles of 16
    f32x4 st[4];
    #pragma unroll
    for(int cc=0; cc<4; cc++){
      bf16x8 bk0 = *(const bf16x8*)&Ks[cc*16 + l16][quad*8];
      bf16x8 bk1 = *(const bf16x8*)&Ks[cc*16 + l16][32 + quad*8];
      f32x4 z = {};
      z = __builtin_amdgcn_mfma_f32_16x16x32_bf16(aq0, bk0, z, 0,0,0);
      z = __builtin_amdgcn_mfma_f32_16x16x32_bf16(aq1, bk1, z, 0,0,0);
      st[cc] = z;
    }
    // online softmax; C-layout row = quad*4 + r, 16 lanes of a quad share rows
    #pragma unroll
    for(int r=0;r<4;r++){
      float s0 = st[0][r]*scale, s1 = st[1][r]*scale;
      float s2 = st[2][r]*scale, s3 = st[3][r]*scale;
      float mx = fmaxf(fmaxf(s0,s1), fmaxf(s2,s3));
      #pragma unroll
      for(int o_=1;o_<16;o_<<=1) mx = fmaxf(mx, __shfl_xor(mx, o_, 16));
      float mnew  = fmaxf(mrow[r], mx);
      float alpha = __expf(mrow[r] - mnew);
      mrow[r] = mnew;
      float p0 = __expf(s0 - mnew), p1 = __expf(s1 - mnew);
      float p2 = __expf(s2 - mnew), p3 = __expf(s3 - mnew);
      st[0][r]=p0; st[1][r]=p1; st[2][r]=p2; st[3][r]=p3;
      float ps = p0+p1+p2+p3;
      #pragma unroll
      for(int o_=1;o_<16;o_<<=1) ps += __shfl_xor(ps, o_, 16);
      lrow[r] = lrow[r]*alpha + ps;
      #pragma unroll
      for(int dn=0;dn<4;dn++) o[dn][r] *= alpha;
    }
    // P: C-layout -> LDS -> A-layout
    #pragma unroll
    for(int cc=0;cc<4;cc++)
      #pragma unroll
      for(int r=0;r<4;r++)
        Ps[wv][quad*4+r][cc*16+l16] = f2b(st[cc][r]);
    __syncthreads();
    bf16x8 ap0 = *(const bf16x8*)&Ps[wv][l16][quad*8];
    bf16x8 ap1 = *(const bf16x8*)&Ps[wv][l16][32 + quad*8];
    #pragma unroll
    for(int dn=0; dn<4; dn++){
      bf16x8 bv0 = *(const bf16x8*)&Vt[dn*16 + l16][quad*8];
      bf16x8 bv1 = *(const bf16x8*)&Vt[dn*16 + l16][32 + quad*8];
      o[dn] = __builtin_amdgcn_mfma_f32_16x16x32_bf16(ap0, bv0, o[dn], 0,0,0);
      o[dn] = __builtin_amdgcn_mfma_f32_16x16x32_bf16(ap1, bv1, o[dn], 0,0,0);
    }
  }
  #pragma unroll
  for(int dn=0;dn<4;dn++)
    #pragma unroll
    for(int r=0;r<4;r++){
      float vv = o[dn][r] / lrow[r];
      AO[(size_t)(b*NQ + qt*64 + wv*16 + quad*4 + r) * DIM + h*HD + dn*16 + l16] = f2b(vv);
    }
}

extern "C" void kernel_launch(void* const* d_in, const int* in_sizes, int n_in,
                              void* d_out, int out_size, void* d_ws, size_t ws_size,
                              hipStream_t stream){
  const float* query   = (const float*)d_in[0];
  const float* context = (const float*)d_in[1];
  const float* ln_w  = (const float*)d_in[2];
  const float* ln_b  = (const float*)d_in[3];
  const float* a1_wq = (const float*)d_in[4];
  const float* a1_wkv= (const float*)d_in[5];
  const float* a1_wp = (const float*)d_in[6];
  const float* a1_bp = (const float*)d_in[7];
  const float* m1_w1 = (const float*)d_in[8];
  const float* m1_b1 = (const float*)d_in[9];
  const float* m1_w2 = (const float*)d_in[10];
  const float* m1_b2 = (const float*)d_in[11];
  const float* a2_wq = (const float*)d_in[12];
  const float* a2_wkv= (const float*)d_in[13];
  const float* a2_wp = (const float*)d_in[14];
  const float* a2_bp = (const float*)d_in[15];
  const float* m2_w1 = (const float*)d_in[16];
  const float* m2_b1 = (const float*)d_in[17];
  const float* m2_w2 = (const float*)d_in[18];
  const float* m2_b2 = (const float*)d_in[19];
  (void)in_sizes; (void)n_in; (void)out_size; (void)ws_size;

  float* c_out = (float*)d_out;                    // output 0: c (8,1024,768) fp32
  float* q_out = c_out + (size_t)B_*NQ*IND;        // output 1: q (8,1024,768) fp32

  char* base = (char*)d_ws;
  size_t off = 0;
  auto alloc = [&](size_t elems)->u16*{
    u16* p = (u16*)(base + off);
    off += ((elems*2) + 255) & ~(size_t)255;
    return p;
  };
  u16* wq1t  = alloc((size_t)DIM*IND);
  u16* wkv1t = alloc((size_t)2*DIM*IND);
  u16* wp1t  = alloc((size_t)IND*DIM);
  u16* w11t  = alloc((size_t)HID*IND);
  u16* w21t  = alloc((size_t)IND*HID);
  u16* wq2t  = alloc((size_t)DIM*IND);
  u16* wkv2t = alloc((size_t)2*DIM*IND);
  u16* wp2t  = alloc((size_t)IND*DIM);
  u16* w12t  = alloc((size_t)HID*IND);
  u16* w22t  = alloc((size_t)IND*HID);
  u16* qn_b  = alloc((size_t)B_*NQ*IND);
  u16* cn_b  = alloc((size_t)B_*NC*IND);
  u16* Tb    = alloc((size_t)B_*NQ*IND);
  u16* Qb    = alloc((size_t)B_*NQ*DIM);
  u16* KVb   = alloc((size_t)B_*NC*2*DIM);
  u16* AOb   = alloc((size_t)B_*NQ*DIM);
  u16* Hb    = alloc((size_t)B_*NQ*HID);

  dim3 tb(32,8);
  wtrans_kernel<<<dim3(DIM/32,   IND/32), tb, 0, stream>>>(a1_wq,  wq1t,  IND, DIM);
  wtrans_kernel<<<dim3(2*DIM/32, IND/32), tb, 0, stream>>>(a1_wkv, wkv1t, IND, 2*DIM);
  wtrans_kernel<<<dim3(IND/32,   DIM/32), tb, 0, stream>>>(a1_wp,  wp1t,  DIM, IND);
  wtrans_kernel<<<dim3(HID/32,   IND/32), tb, 0, stream>>>(m1_w1,  w11t,  IND, HID);
  wtrans_kernel<<<dim3(IND/32,   HID/32), tb, 0, stream>>>(m1_w2,  w21t,  HID, IND);
  wtrans_kernel<<<dim3(DIM/32,   IND/32), tb, 0, stream>>>(a2_wq,  wq2t,  IND, DIM);
  wtrans_kernel<<<dim3(2*DIM/32, IND/32), tb, 0, stream>>>(a2_wkv, wkv2t, IND, 2*DIM);
  wtrans_kernel<<<dim3(IND/32,   DIM/32), tb, 0, stream>>>(a2_wp,  wp2t,  DIM, IND);
  wtrans_kernel<<<dim3(HID/32,   IND/32), tb, 0, stream>>>(m2_w1,  w12t,  IND, HID);
  wtrans_kernel<<<dim3(IND/32,   HID/32), tb, 0, stream>>>(m2_w2,  w22t,  HID, IND);

  // q = LN(query) -> bf16 (GEMM input) + fp32 (final output 1)
  ln_kernel<true ><<<B_*NQ, 256, 0, stream>>>(query,   ln_w, ln_b, qn_b, q_out);
  ln_kernel<false><<<B_*NC, 256, 0, stream>>>(context, ln_w, ln_b, cn_b, nullptr);

  // --- block 1: cross-attention ---
  gemm_bt<0,false,false><<<dim3(B_*NQ/128, DIM/128),   256, 0, stream>>>(qn_b, wq1t,  nullptr, Qb,  IND, DIM);
  gemm_bt<0,false,false><<<dim3(B_*NC/128, 2*DIM/128), 256, 0, stream>>>(cn_b, wkv1t, nullptr, KVb, IND, 2*DIM);
  attn_kernel<<<B_*NH*(NQ/64), 256, 0, stream>>>(Qb, KVb, AOb, NC);
  gemm_bt<1,true,false><<<dim3(B_*NQ/128, IND/128), 256, 0, stream>>>(AOb, wp1t, a1_bp, c_out, DIM, IND);
  // --- MLP 1 ---
  ln_kernel<false><<<B_*NQ, 256, 0, stream>>>(c_out, ln_w, ln_b, Tb, nullptr);
  gemm_bt<0,true,true ><<<dim3(B_*NQ/128, HID/128), 256, 0, stream>>>(Tb, w11t, m1_b1, Hb, IND, HID);
  gemm_bt<2,true,false><<<dim3(B_*NQ/128, IND/128), 256, 0, stream>>>(Hb, w21t, m1_b2, c_out, HID, IND);
  // --- block 2: cross-attention (q reused, kv from LN(c)) ---
  ln_kernel<false><<<B_*NQ, 256, 0, stream>>>(c_out, ln_w, ln_b, Tb, nullptr);
  gemm_bt<0,false,false><<<dim3(B_*NQ/128, DIM/128),   256, 0, stream>>>(qn_b, wq2t,  nullptr, Qb,  IND, DIM);
  gemm_bt<0,false,false><<<dim3(B_*NQ/128, 2*DIM/128), 256, 0, stream>>>(Tb,   wkv2t, nullptr, KVb, IND, 2*DIM);
  attn_kernel<<<B_*NH*(NQ/64), 256, 0, stream>>>(Qb, KVb, AOb, NQ);
  gemm_bt<2,true,false><<<dim3(B_*NQ/128, IND/128), 256, 0, stream>>>(AOb, wp2t, a2_bp, c_out, DIM, IND);
  // --- MLP 2 ---
  ln_kernel<false><<<B_*NQ, 256, 0, stream>>>(c_out, ln_w, ln_b, Tb, nullptr);
  gemm_bt<0,true,true ><<<dim3(B_*NQ/128, HID/128), 256, 0, stream>>>(Tb, w12t, m2_b1, Hb, IND, HID);
  gemm_bt<2,true,false><<<dim3(B_*NQ/128, IND/128), 256, 0, stream>>>(Hb, w22t, m2_b2, c_out, HID, IND);
}